// Round 18
// baseline (84.962 us; speedup 1.0000x reference)
//
#include <hip/hip_runtime.h>

#define B_ 2
#define S_ 2048
#define D_ 1024
#define H_ 16
#define DH_ 64
#define NP_ 2048  // partial tiles: 32 bh * 64 qt32

typedef short v8s __attribute__((ext_vector_type(8)));
typedef float v4f __attribute__((ext_vector_type(4)));
typedef float v16f __attribute__((ext_vector_type(16)));
typedef unsigned int v2u __attribute__((ext_vector_type(2)));
typedef unsigned int v4u __attribute__((ext_vector_type(4)));
typedef unsigned int uint32;

__device__ inline short f2bf(float f) {
  unsigned u = __float_as_uint(f);
  u = (u + 0x7FFFu + ((u >> 16) & 1u)) >> 16;
  return (short)u;
}

__device__ inline unsigned pk_bf16(float lo, float hi) {
  unsigned r;
  asm("v_cvt_pk_bf16_f32 %0, %1, %2" : "=v"(r) : "v"(lo), "v"(hi));
  return r;
}

__device__ inline void gll16(const void* g, void* l) {
  __builtin_amdgcn_global_load_lds(
      (const __attribute__((address_space(1))) void*)g,
      (__attribute__((address_space(3))) void*)l, 16, 0, 0);
}

// ---------------- merged pre-convert kernel ----------------
__global__ __launch_bounds__(256) void cvt_all_kernel(
    const float* __restrict__ k, short* __restrict__ kb,
    const float* __restrict__ v, short* __restrict__ vt,
    const float* __restrict__ w, short* __restrict__ wt) {
  __shared__ short t[64][64 + 8];
  int bid = blockIdx.x;
  int tid = threadIdx.x;
  if (bid < 2048) {
    int i = bid * 256 + tid;
    float4 a = ((const float4*)k)[2 * i];
    float4 b = ((const float4*)k)[2 * i + 1];
    v8s o;
    o[0] = f2bf(a.x); o[1] = f2bf(a.y); o[2] = f2bf(a.z); o[3] = f2bf(a.w);
    o[4] = f2bf(b.x); o[5] = f2bf(b.y); o[6] = f2bf(b.z); o[7] = f2bf(b.w);
    ((v8s*)kb)[i] = o;
    return;
  }
  int r = tid >> 2, c16 = (tid & 3) * 16;
  if (bid < 3072) {
    int id = bid - 2048;
    int st = id & 31;
    int bh = id >> 5;
    int b = bh >> 4, h = bh & 15;
    const float* vp = v + ((size_t)(b * S_ + st * 64 + r)) * D_ + h * DH_ + c16;
    for (int i = 0; i < 16; i += 4) {
      float4 a = *(const float4*)(vp + i);
      t[r][c16 + i + 0] = f2bf(a.x);
      t[r][c16 + i + 1] = f2bf(a.y);
      t[r][c16 + i + 2] = f2bf(a.z);
      t[r][c16 + i + 3] = f2bf(a.w);
    }
    __syncthreads();
    short* op = vt + ((size_t)((b * H_ + h) * DH_ + r)) * S_ + st * 64 + c16;
    v8s o0, o1;
    for (int j = 0; j < 8; ++j) { o0[j] = t[c16 + j][r]; o1[j] = t[c16 + 8 + j][r]; }
    *(v8s*)op = o0;
    *(v8s*)(op + 8) = o1;
  } else {
    int id = bid - 3072;
    int tk = id & 15, tm = id >> 4;
    const float* wp = w + (size_t)(tk * 64 + r) * D_ + tm * 64 + c16;
    for (int i = 0; i < 16; i += 4) {
      float4 a = *(const float4*)(wp + i);
      t[r][c16 + i + 0] = f2bf(a.x);
      t[r][c16 + i + 1] = f2bf(a.y);
      t[r][c16 + i + 2] = f2bf(a.z);
      t[r][c16 + i + 3] = f2bf(a.w);
    }
    __syncthreads();
    short* op = wt + (size_t)(tm * 64 + r) * D_ + tk * 64 + c16;
    v8s o0, o1;
    for (int j = 0; j < 8; ++j) { o0[j] = t[c16 + j][r]; o1[j] = t[c16 + 8 + j][r]; }
    *(v8s*)op = o0;
    *(v8s*)(op + 8) = o1;
  }
}

// ---------------- split-K flash attention, QBLK=256 / 8 waves ---------------
// 32*8*SPLITS blocks x 512 thr. Block = (bh, qt256, sp); 8 waves share one
// 16KB K/V tile (waves 0-3 stage K, 4-7 stage V; 2 gll16/thread); each wave
// owns 32 q-rows. seg = 4(qt+1)/SPLITS K64-tiles per block. sidx map: every
// CU's SPLITS blocks sum to exactly 18 staged tiles (g=sidx>>3, s=sidx&7).
template <int SPLITS>
__global__ __launch_bounds__(512, 4) void attn_kernel(
    const float* __restrict__ q, const short* __restrict__ kbf,
    const short* __restrict__ vtb, uint32* __restrict__ Opart,
    float* __restrict__ Lsum, const float* __restrict__ residual,
    float* __restrict__ res_out) {
  int bid = blockIdx.x;
  int bh = bid & 31;
  int sidx = bid >> 5;
  int g = sidx >> 3, s = sidx & 7;
  int qt = (g & 1) ? s : 7 - s;
  int sp = g;
  int b = bh >> 4, h = bh & 15;

  const int seg = (4 * (qt + 1)) / SPLITS;
  const int t0 = sp * seg;
  const int t1 = t0 + seg - 1;  // inclusive

  int tid = threadIdx.x;
  int wave = tid >> 6, lane = tid & 63;
  int l31 = lane & 31, h32 = lane >> 5;

  __shared__ short Klds[64][64];  // [key][d] swizzled
  __shared__ short Vlds[64][64];  // [d][key] swizzled

  const int qrow0 = qt * 256 + wave * 32;
  const int lr8 = lane >> 3;
  const int scol = ((lane & 7) ^ lr8) << 3;

  // staging roles: waves 0-3 -> K rows sw*8+lr8 (+32); waves 4-7 -> V
  const int sw = wave & 3;
  const short* pk_ = kbf + (size_t)b * S_ * D_ + h * DH_ +
                     (size_t)(t0 * 64 + sw * 8 + lr8) * D_ + scol;
  const short* pv_ = vtb + (size_t)(b * H_ + h) * DH_ * S_ +
                     (size_t)(sw * 8 + lr8) * S_ + t0 * 64 + scol;

  // Q fragments pre-scaled by 0.125*log2e: lane holds Q^T[d][q=l31]
  v8s qf[4];
  {
    const float* qp = q + (size_t)(b * S_ + qrow0 + l31) * D_ + h * DH_ + h32 * 8;
    const float sc = 0.125f * 1.44269504f;
#pragma unroll
    for (int d4 = 0; d4 < 4; ++d4) {
      float4 x = *(const float4*)(qp + d4 * 16);
      float4 y = *(const float4*)(qp + d4 * 16 + 4);
      v8s tq;
      tq[0] = f2bf(x.x * sc); tq[1] = f2bf(x.y * sc);
      tq[2] = f2bf(x.z * sc); tq[3] = f2bf(x.w * sc);
      tq[4] = f2bf(y.x * sc); tq[5] = f2bf(y.y * sc);
      tq[6] = f2bf(y.z * sc); tq[7] = f2bf(y.w * sc);
      qf[d4] = tq;
    }
  }

  v16f O0, O1;
#pragma unroll
  for (int r = 0; r < 16; ++r) { O0[r] = 0.f; O1[r] = 0.f; }
  float L = 0.f;
  const int swz = (l31 & 7) << 3;

  for (int ss = t0; ss <= t1; ++ss) {
    // stage K/V tile (single buffer, split across wave quads)
    if (wave < 4) {
      gll16(pk_, &Klds[sw * 8][0]);
      gll16(pk_ + (size_t)32 * D_, &Klds[32 + sw * 8][0]);
    } else {
      gll16(pv_, &Vlds[sw * 8][0]);
      gll16(pv_ + (size_t)32 * S_, &Vlds[32 + sw * 8][0]);
    }
    pk_ += (size_t)64 * D_;
    pv_ += 64;
    asm volatile("s_waitcnt vmcnt(0)" ::: "memory");
    __builtin_amdgcn_sched_barrier(0);
    __builtin_amdgcn_s_barrier();
    __builtin_amdgcn_sched_barrier(0);

    int kb = ss * 64;
    bool fullskip = (kb >= qrow0 + 32);  // entire tile masked for this wave
    if (!fullskip) {
      bool skip1 = (kb >= qrow0);  // keys kb+32.. all masked for this wave
      bool msk = (kb + 63 > qrow0);

      // QK^T swapped: S^T[k][q], k rows per lane = (r&3)+8*(r>>2)+4*h32 (+32)
      __builtin_amdgcn_s_setprio(1);
      v16f S0, S1;
#pragma unroll
      for (int r = 0; r < 16; ++r) { S0[r] = 0.f; S1[r] = 0.f; }
#pragma unroll
      for (int d4 = 0; d4 < 4; ++d4) {
        v8s kf = *(const v8s*)&Klds[l31][(((d4 << 1) | h32) << 3) ^ swz];
        S0 = __builtin_amdgcn_mfma_f32_32x32x16_bf16(kf, qf[d4], S0, 0, 0, 0);
      }
      if (!skip1) {
#pragma unroll
        for (int d4 = 0; d4 < 4; ++d4) {
          v8s kf = *(const v8s*)&Klds[32 + l31][(((d4 << 1) | h32) << 3) ^ swz];
          S1 = __builtin_amdgcn_mfma_f32_32x32x16_bf16(kf, qf[d4], S1, 0, 0, 0);
        }
      }
      __builtin_amdgcn_s_setprio(0);

      int qg = qrow0 + l31;
      if (msk) {
#pragma unroll
        for (int r = 0; r < 16; ++r) {
          int kl = kb + (r & 3) + 8 * (r >> 2) + 4 * h32;
          if (kl > qg) S0[r] = -1e30f;
        }
        if (!skip1) {
#pragma unroll
          for (int r = 0; r < 16; ++r) {
            int kl = kb + 32 + (r & 3) + 8 * (r >> 2) + 4 * h32;
            if (kl > qg) S1[r] = -1e30f;
          }
        }
      }

      float rs = 0.f;
      unsigned pw0[8], pw1[8];
#pragma unroll
      for (int r = 0; r < 16; ++r) {
        S0[r] = __builtin_amdgcn_exp2f(S0[r]);
        rs += S0[r];
      }
#pragma unroll
      for (int w = 0; w < 8; ++w) pw0[w] = pk_bf16(S0[2 * w], S0[2 * w + 1]);
      if (!skip1) {
#pragma unroll
        for (int r = 0; r < 16; ++r) {
          S1[r] = __builtin_amdgcn_exp2f(S1[r]);
          rs += S1[r];
        }
#pragma unroll
        for (int w = 0; w < 8; ++w) pw1[w] = pk_bf16(S1[2 * w], S1[2 * w + 1]);
      }
      rs += __shfl_xor(rs, 32);
      L += rs;

      // PV: O^T[d][q] += V^T[d][k] P^T[k][q]; B-frag via permlane32_swap
      __builtin_amdgcn_s_setprio(1);
#pragma unroll
      for (int ks = 0; ks < 2; ++ks) {
        v2u a = __builtin_amdgcn_permlane32_swap(pw0[ks * 4 + 0], pw0[ks * 4 + 2], false, false);
        v2u c = __builtin_amdgcn_permlane32_swap(pw0[ks * 4 + 1], pw0[ks * 4 + 3], false, false);
        v4u fw; fw.x = a.x; fw.y = c.x; fw.z = a.y; fw.w = c.y;
        v8s pb = __builtin_bit_cast(v8s, fw);
        v8s vf0 = *(const v8s*)&Vlds[l31][(((ks << 1) | h32) << 3) ^ swz];
        O0 = __builtin_amdgcn_mfma_f32_32x32x16_bf16(vf0, pb, O0, 0, 0, 0);
        v8s vf1 = *(const v8s*)&Vlds[32 + l31][(((ks << 1) | h32) << 3) ^ swz];
        O1 = __builtin_amdgcn_mfma_f32_32x32x16_bf16(vf1, pb, O1, 0, 0, 0);
      }
      if (!skip1) {
#pragma unroll
        for (int ks = 0; ks < 2; ++ks) {
          v2u a = __builtin_amdgcn_permlane32_swap(pw1[ks * 4 + 0], pw1[ks * 4 + 2], false, false);
          v2u c = __builtin_amdgcn_permlane32_swap(pw1[ks * 4 + 1], pw1[ks * 4 + 3], false, false);
          v4u fw; fw.x = a.x; fw.y = c.x; fw.z = a.y; fw.w = c.y;
          v8s pb = __builtin_bit_cast(v8s, fw);
          v8s vf0 = *(const v8s*)&Vlds[l31][((((ks + 2) << 1) | h32) << 3) ^ swz];
          O0 = __builtin_amdgcn_mfma_f32_32x32x16_bf16(vf0, pb, O0, 0, 0, 0);
          v8s vf1 = *(const v8s*)&Vlds[32 + l31][((((ks + 2) << 1) | h32) << 3) ^ swz];
          O1 = __builtin_amdgcn_mfma_f32_32x32x16_bf16(vf1, pb, O1, 0, 0, 0);
        }
      }
      __builtin_amdgcn_s_setprio(0);
    }

    __builtin_amdgcn_sched_barrier(0);
    __builtin_amdgcn_s_barrier();  // all reads done before next stage rewrite
    __builtin_amdgcn_sched_barrier(0);
  }

  // Epilogue: unnormalized partial write (native layout, coalesced in q)
  int p = bh * 64 + qt * 8 + wave;
  uint32* Op = Opart + ((size_t)(sp * NP_ + p)) * 1024;
#pragma unroll
  for (int w = 0; w < 8; ++w) {
    int dpair = 4 * (w >> 1) + (w & 1) + 2 * h32;
    Op[dpair * 32 + l31] = pk_bf16(O0[2 * w], O0[2 * w + 1]);
    Op[(16 + dpair) * 32 + l31] = pk_bf16(O1[2 * w], O1[2 * w + 1]);
  }
  if (h32 == 0) Lsum[(size_t)(sp * NP_ + p) * 32 + l31] = L;

  // Folded residual pass-through: out[0:B*S*D] = residual (grid-strided)
  {
    constexpr int NBLK = 32 * 8 * SPLITS;
    const float4* rs_ = (const float4*)residual;
    float4* rd_ = (float4*)res_out;
    for (size_t idx = (size_t)bid * 512 + tid; idx < 1048576;
         idx += (size_t)NBLK * 512)
      rd_[idx] = rs_[idx];
  }
}

// ---------------- merge partials -> z (bf16) ----------------
template <int SPLITS>
__global__ __launch_bounds__(128) void merge_kernel(
    const uint32* __restrict__ Opart, const float* __restrict__ Lsum,
    short* __restrict__ z) {
  int p = blockIdx.x;
  int tid = threadIdx.x;
  int qq = tid & 31, g = tid >> 5;

  float Lt = 0.f;
#pragma unroll
  for (int sp = 0; sp < SPLITS; ++sp)
    Lt += Lsum[((size_t)sp * NP_ + p) * 32 + qq];
  float f = 1.f / Lt;

  __shared__ uint32 T[32][33];
#pragma unroll
  for (int j = 0; j < 8; ++j) {
    int dp = g * 8 + j;
    float lo = 0.f, hi = 0.f;
#pragma unroll
    for (int sp = 0; sp < SPLITS; ++sp) {
      uint32 u = Opart[((size_t)sp * NP_ + p) * 1024 + dp * 32 + qq];
      lo += __uint_as_float(u << 16);
      hi += __uint_as_float(u & 0xFFFF0000u);
    }
    T[qq][dp] = pk_bf16(lo * f, hi * f);
  }
  __syncthreads();
  int q2 = tid >> 2, c = (tid & 3) * 8;
  int srow = (p & 63) * 32 + q2;
  int b = p >> 10, h = (p >> 6) & 15;
  uint32* zp = (uint32*)z + ((size_t)(b * S_ + srow)) * (D_ / 2) + h * 32 + c;
#pragma unroll
  for (int j = 0; j < 8; ++j) zp[j] = T[q2][c + j];
}

// ------------- projection GEMM 128x128 (R14-proven): out = z @ Wt^T + b -----
__global__ __launch_bounds__(256) void proj_kernel(
    const short* __restrict__ z, const short* __restrict__ wt,
    const float* __restrict__ bias, float* __restrict__ out) {
  int bid = blockIdx.x;
  int bm = bid & 31, bn = bid >> 5;
  int tid = threadIdx.x;
  int wave = tid >> 6, lane = tid & 63, lh = lane >> 4, ll = lane & 15;
  int wr = wave >> 1, wc = wave & 1;

  __shared__ short Al[2][128][64];
  __shared__ short Bl[2][128][64];

  const int r8 = lane >> 3;
  const int scol = ((lane & 7) ^ r8) << 3;

  v4f acc[4][4];
#pragma unroll
  for (int m = 0; m < 4; ++m)
#pragma unroll
    for (int n = 0; n < 4; ++n) acc[m][n] = (v4f){0.f, 0.f, 0.f, 0.f};

  auto stage = [&](int kb, int bbuf) {
#pragma unroll
    for (int i = 0; i < 4; ++i) {
      int c = wave * 4 + i;
      gll16(z + (size_t)(bm * 128 + c * 8 + r8) * D_ + kb + scol, &Al[bbuf][c * 8][0]);
    }
#pragma unroll
    for (int i = 0; i < 4; ++i) {
      int c = wave * 4 + i;
      gll16(wt + (size_t)(bn * 128 + c * 8 + r8) * D_ + kb + scol, &Bl[bbuf][c * 8][0]);
    }
  };

  stage(0, 0);
  __syncthreads();

  for (int kt = 0; kt < D_ / 64; ++kt) {
    int bbuf = kt & 1;
    if (kt + 1 < D_ / 64) stage((kt + 1) * 64, bbuf ^ 1);
    v8s af[4][2], bf[4][2];
#pragma unroll
    for (int m = 0; m < 4; ++m) {
      int row = wr * 64 + m * 16 + ll;
#pragma unroll
      for (int c = 0; c < 2; ++c)
        af[m][c] = *(const v8s*)&Al[bbuf][row][(((c << 2) | lh) ^ (ll & 7)) << 3];
    }
#pragma unroll
    for (int n = 0; n < 4; ++n) {
      int row = wc * 64 + n * 16 + ll;
#pragma unroll
      for (int c = 0; c < 2; ++c)
        bf[n][c] = *(const v8s*)&Bl[bbuf][row][(((c << 2) | lh) ^ (ll & 7)) << 3];
    }
#pragma unroll
    for (int m = 0; m < 4; ++m)
#pragma unroll
      for (int n = 0; n < 4; ++n)
#pragma unroll
        for (int c = 0; c < 2; ++c)
          acc[m][n] = __builtin_amdgcn_mfma_f32_16x16x32_bf16(af[m][c], bf[n][c], acc[m][n], 0, 0, 0);
    __syncthreads();
  }

#pragma unroll
  for (int m = 0; m < 4; ++m) {
    int gr = bm * 128 + wr * 64 + m * 16 + lh * 4;
#pragma unroll
    for (int n = 0; n < 4; ++n) {
      int gc = bn * 128 + wc * 64 + n * 16 + ll;
      float bo = bias[gc];
#pragma unroll
      for (int r = 0; r < 4; ++r)
        out[(size_t)(gr + r) * D_ + gc] = acc[m][n][r] + bo;
    }
  }
}

extern "C" void kernel_launch(void* const* d_in, const int* in_sizes, int n_in,
                              void* d_out, int out_size, void* d_ws, size_t ws_size,
                              hipStream_t stream) {
  const float* residual = (const float*)d_in[0];
  const float* q = (const float*)d_in[1];
  const float* k = (const float*)d_in[2];
  const float* v = (const float*)d_in[3];
  const float* W = (const float*)d_in[4];
  const float* bO = (const float*)d_in[5];
  float* out = (float*)d_out;

  const size_t half = (size_t)B_ * S_ * D_;
  char* ws = (char*)d_ws;
  short* kbf = (short*)ws;                      // 8.4 MB (reused as z by merge)
  short* vtb = kbf + half;                      // 8.4 MB
  short* wtb = vtb + half;                      // 2.1 MB
  char* pbase = (char*)(wtb + (size_t)D_ * D_);
  const size_t opart_b = (size_t)NP_ * 1024 * 4;  // per slot: 8.4 MB
  const size_t l_b = (size_t)NP_ * 32 * 4;        // per slot: 256 KB
  const size_t base_b = (size_t)pbase - (size_t)ws;
  short* z = kbf;  // kbf dead after attn; merge writes z there

  cvt_all_kernel<<<3328, 256, 0, stream>>>(k, kbf, v, vtb, W, wtb);

  if (ws_size >= base_b + 4 * (opart_b + l_b)) {
    uint32* Opart = (uint32*)pbase;
    float* Lsum = (float*)(pbase + 4 * opart_b);
    attn_kernel<4><<<1024, 512, 0, stream>>>(q, kbf, vtb, Opart, Lsum, residual, out);
    merge_kernel<4><<<NP_, 128, 0, stream>>>(Opart, Lsum, z);
  } else {
    uint32* Opart = (uint32*)pbase;
    float* Lsum = (float*)(pbase + 2 * opart_b);
    attn_kernel<2><<<512, 512, 0, stream>>>(q, kbf, vtb, Opart, Lsum, residual, out);
    merge_kernel<2><<<NP_, 128, 0, stream>>>(Opart, Lsum, z);
  }
  proj_kernel<<<256, 256, 0, stream>>>(z, wtb, bO, out + half);
}

// Round 19
// 68.267 us; speedup vs baseline: 1.2445x; 1.2445x over previous
//
#include <hip/hip_runtime.h>

#define B_ 2
#define S_ 2048
#define D_ 1024
#define H_ 16
#define DH_ 64
#define NP_ 2048  // partial tiles: 32 bh * 64 qt32

typedef short v8s __attribute__((ext_vector_type(8)));
typedef float v4f __attribute__((ext_vector_type(4)));
typedef float v16f __attribute__((ext_vector_type(16)));
typedef unsigned int v2u __attribute__((ext_vector_type(2)));
typedef unsigned int v4u __attribute__((ext_vector_type(4)));
typedef unsigned int uint32;

__device__ inline short f2bf(float f) {
  unsigned u = __float_as_uint(f);
  u = (u + 0x7FFFu + ((u >> 16) & 1u)) >> 16;
  return (short)u;
}

__device__ inline unsigned pk_bf16(float lo, float hi) {
  unsigned r;
  asm("v_cvt_pk_bf16_f32 %0, %1, %2" : "=v"(r) : "v"(lo), "v"(hi));
  return r;
}

__device__ inline void gll16(const void* g, void* l) {
  __builtin_amdgcn_global_load_lds(
      (const __attribute__((address_space(1))) void*)g,
      (__attribute__((address_space(3))) void*)l, 16, 0, 0);
}

// ---------------- merged pre-convert kernel ----------------
__global__ __launch_bounds__(256) void cvt_all_kernel(
    const float* __restrict__ k, short* __restrict__ kb,
    const float* __restrict__ v, short* __restrict__ vt,
    const float* __restrict__ w, short* __restrict__ wt) {
  __shared__ short t[64][64 + 8];
  int bid = blockIdx.x;
  int tid = threadIdx.x;
  if (bid < 2048) {
    int i = bid * 256 + tid;
    float4 a = ((const float4*)k)[2 * i];
    float4 b = ((const float4*)k)[2 * i + 1];
    v8s o;
    o[0] = f2bf(a.x); o[1] = f2bf(a.y); o[2] = f2bf(a.z); o[3] = f2bf(a.w);
    o[4] = f2bf(b.x); o[5] = f2bf(b.y); o[6] = f2bf(b.z); o[7] = f2bf(b.w);
    ((v8s*)kb)[i] = o;
    return;
  }
  int r = tid >> 2, c16 = (tid & 3) * 16;
  if (bid < 3072) {
    int id = bid - 2048;
    int st = id & 31;
    int bh = id >> 5;
    int b = bh >> 4, h = bh & 15;
    const float* vp = v + ((size_t)(b * S_ + st * 64 + r)) * D_ + h * DH_ + c16;
    for (int i = 0; i < 16; i += 4) {
      float4 a = *(const float4*)(vp + i);
      t[r][c16 + i + 0] = f2bf(a.x);
      t[r][c16 + i + 1] = f2bf(a.y);
      t[r][c16 + i + 2] = f2bf(a.z);
      t[r][c16 + i + 3] = f2bf(a.w);
    }
    __syncthreads();
    short* op = vt + ((size_t)((b * H_ + h) * DH_ + r)) * S_ + st * 64 + c16;
    v8s o0, o1;
    for (int j = 0; j < 8; ++j) { o0[j] = t[c16 + j][r]; o1[j] = t[c16 + 8 + j][r]; }
    *(v8s*)op = o0;
    *(v8s*)(op + 8) = o1;
  } else {
    int id = bid - 3072;
    int tk = id & 15, tm = id >> 4;
    const float* wp = w + (size_t)(tk * 64 + r) * D_ + tm * 64 + c16;
    for (int i = 0; i < 16; i += 4) {
      float4 a = *(const float4*)(wp + i);
      t[r][c16 + i + 0] = f2bf(a.x);
      t[r][c16 + i + 1] = f2bf(a.y);
      t[r][c16 + i + 2] = f2bf(a.z);
      t[r][c16 + i + 3] = f2bf(a.w);
    }
    __syncthreads();
    short* op = wt + (size_t)(tm * 64 + r) * D_ + tk * 64 + c16;
    v8s o0, o1;
    for (int j = 0; j < 8; ++j) { o0[j] = t[c16 + j][r]; o1[j] = t[c16 + 8 + j][r]; }
    *(v8s*)op = o0;
    *(v8s*)(op + 8) = o1;
  }
}

// -------- split-K flash attention, QBLK=128 / 4 waves / dbuf KT=64 ----------
// R17 winning structure + counted-vmcnt double-buffer: stage(s+1,buf^1),
// vmcnt(4) (tile-s's own 4 loads done), barrier, compute(s) while s+1 flies.
// 32KB LDS, 4 blocks/CU, 16 waves/CU. Prologue parity = t0&1 (R10 lesson).
template <int SPLITS>
__global__ __launch_bounds__(256, 4) void attn_kernel(
    const float* __restrict__ q, const short* __restrict__ kbf,
    const short* __restrict__ vtb, uint32* __restrict__ Opart,
    float* __restrict__ Lsum, const float* __restrict__ residual,
    float* __restrict__ res_out) {
  int bid = blockIdx.x;
  int bh = bid & 31;
  int sp = (SPLITS == 2) ? ((bid >> 5) & 1) : 0;
  int t = (SPLITS == 2) ? (bid >> 6) : (bid >> 5);  // 0..15
  int g = t >> 2;
  int qt = (g == 0) ? 15 - t : (g == 1) ? t - 4 : (g == 2) ? 19 - t : t - 8;
  int b = bh >> 4, h = bh & 15;

  const int nt = 2 * qt + 2;  // K64-tiles for this 128-row q-tile
  const int t0 = (SPLITS == 2 && sp == 1) ? qt + 1 : 0;
  const int t1 = (SPLITS == 2 && sp == 0) ? qt : nt - 1;  // inclusive

  int tid = threadIdx.x;
  int wave = tid >> 6, lane = tid & 63;
  int l31 = lane & 31, h32 = lane >> 5;

  __shared__ short Klds[2][64][64];  // [key][d] swizzled, double-buffered
  __shared__ short Vlds[2][64][64];  // [d][key] swizzled, double-buffered

  const int qrow0 = qt * 128 + wave * 32;
  const int lr8 = lane >> 3;
  const int scol = ((lane & 7) ^ lr8) << 3;

  // staging roles: waves 0-1 -> K rows sw*8+lr8 (+16i); waves 2-3 -> V
  const int sw = wave & 1;
  const short* kbase = kbf + (size_t)b * S_ * D_ + h * DH_ +
                       (size_t)(sw * 8 + lr8) * D_ + scol;
  const short* vbase = vtb + (size_t)(b * H_ + h) * DH_ * S_ +
                       (size_t)(sw * 8 + lr8) * S_ + scol;

  // Q fragments pre-scaled by 0.125*log2e: lane holds Q^T[d][q=l31]
  v8s qf[4];
  {
    const float* qp = q + (size_t)(b * S_ + qrow0 + l31) * D_ + h * DH_ + h32 * 8;
    const float sc = 0.125f * 1.44269504f;
#pragma unroll
    for (int d4 = 0; d4 < 4; ++d4) {
      float4 x = *(const float4*)(qp + d4 * 16);
      float4 y = *(const float4*)(qp + d4 * 16 + 4);
      v8s tq;
      tq[0] = f2bf(x.x * sc); tq[1] = f2bf(x.y * sc);
      tq[2] = f2bf(x.z * sc); tq[3] = f2bf(x.w * sc);
      tq[4] = f2bf(y.x * sc); tq[5] = f2bf(y.y * sc);
      tq[6] = f2bf(y.z * sc); tq[7] = f2bf(y.w * sc);
      qf[d4] = tq;
    }
  }

  v16f O0, O1;
#pragma unroll
  for (int r = 0; r < 16; ++r) { O0[r] = 0.f; O1[r] = 0.f; }
  float L = 0.f;
  const int swz = (l31 & 7) << 3;

  auto stage = [&](int tt, int buf) {
    if (wave < 2) {
      const short* kp = kbase + (size_t)(tt * 64) * D_;
#pragma unroll
      for (int i = 0; i < 4; ++i)
        gll16(kp + (size_t)(i * 16) * D_, &Klds[buf][i * 16 + sw * 8][0]);
    } else {
      const short* vp = vbase + tt * 64;
#pragma unroll
      for (int i = 0; i < 4; ++i)
        gll16(vp + (size_t)(i * 16) * S_, &Vlds[buf][i * 16 + sw * 8][0]);
    }
  };

  stage(t0, t0 & 1);  // prologue parity matches loop's cur = s & 1

  for (int s = t0; s <= t1; ++s) {
    int cur = s & 1;
    if (s < t1) {
      stage(s + 1, cur ^ 1);
      asm volatile("s_waitcnt vmcnt(4)" ::: "memory");  // tile-s loads landed
    } else {
      asm volatile("s_waitcnt vmcnt(0)" ::: "memory");
    }
    __builtin_amdgcn_sched_barrier(0);
    __builtin_amdgcn_s_barrier();
    __builtin_amdgcn_sched_barrier(0);

    int kb = s * 64;
    bool fullskip = (kb >= qrow0 + 32);  // entire tile masked for this wave
    if (!fullskip) {
      bool skip1 = (kb >= qrow0);  // keys kb+32.. all masked for this wave
      bool msk = (kb + 63 > qrow0);

      // QK^T swapped: S^T[k][q], k rows per lane = (r&3)+8*(r>>2)+4*h32 (+32)
      __builtin_amdgcn_s_setprio(1);
      v16f S0, S1;
#pragma unroll
      for (int r = 0; r < 16; ++r) { S0[r] = 0.f; S1[r] = 0.f; }
#pragma unroll
      for (int d4 = 0; d4 < 4; ++d4) {
        v8s kf = *(const v8s*)&Klds[cur][l31][(((d4 << 1) | h32) << 3) ^ swz];
        S0 = __builtin_amdgcn_mfma_f32_32x32x16_bf16(kf, qf[d4], S0, 0, 0, 0);
      }
      if (!skip1) {
#pragma unroll
        for (int d4 = 0; d4 < 4; ++d4) {
          v8s kf = *(const v8s*)&Klds[cur][32 + l31][(((d4 << 1) | h32) << 3) ^ swz];
          S1 = __builtin_amdgcn_mfma_f32_32x32x16_bf16(kf, qf[d4], S1, 0, 0, 0);
        }
      }
      __builtin_amdgcn_s_setprio(0);

      int qg = qrow0 + l31;
      if (msk) {
#pragma unroll
        for (int r = 0; r < 16; ++r) {
          int kl = kb + (r & 3) + 8 * (r >> 2) + 4 * h32;
          if (kl > qg) S0[r] = -1e30f;
        }
        if (!skip1) {
#pragma unroll
          for (int r = 0; r < 16; ++r) {
            int kl = kb + 32 + (r & 3) + 8 * (r >> 2) + 4 * h32;
            if (kl > qg) S1[r] = -1e30f;
          }
        }
      }

      float rs = 0.f;
      unsigned pw0[8], pw1[8];
#pragma unroll
      for (int r = 0; r < 16; ++r) {
        S0[r] = __builtin_amdgcn_exp2f(S0[r]);
        rs += S0[r];
      }
#pragma unroll
      for (int w = 0; w < 8; ++w) pw0[w] = pk_bf16(S0[2 * w], S0[2 * w + 1]);
      if (!skip1) {
#pragma unroll
        for (int r = 0; r < 16; ++r) {
          S1[r] = __builtin_amdgcn_exp2f(S1[r]);
          rs += S1[r];
        }
#pragma unroll
        for (int w = 0; w < 8; ++w) pw1[w] = pk_bf16(S1[2 * w], S1[2 * w + 1]);
      }
      rs += __shfl_xor(rs, 32);
      L += rs;

      // PV: O^T[d][q] += V^T[d][k] P^T[k][q]; B-frag via permlane32_swap
      __builtin_amdgcn_s_setprio(1);
#pragma unroll
      for (int ks = 0; ks < 2; ++ks) {
        v2u a = __builtin_amdgcn_permlane32_swap(pw0[ks * 4 + 0], pw0[ks * 4 + 2], false, false);
        v2u c = __builtin_amdgcn_permlane32_swap(pw0[ks * 4 + 1], pw0[ks * 4 + 3], false, false);
        v4u fw; fw.x = a.x; fw.y = c.x; fw.z = a.y; fw.w = c.y;
        v8s pb = __builtin_bit_cast(v8s, fw);
        v8s vf0 = *(const v8s*)&Vlds[cur][l31][(((ks << 1) | h32) << 3) ^ swz];
        O0 = __builtin_amdgcn_mfma_f32_32x32x16_bf16(vf0, pb, O0, 0, 0, 0);
        v8s vf1 = *(const v8s*)&Vlds[cur][32 + l31][(((ks << 1) | h32) << 3) ^ swz];
        O1 = __builtin_amdgcn_mfma_f32_32x32x16_bf16(vf1, pb, O1, 0, 0, 0);
      }
      if (!skip1) {
#pragma unroll
        for (int ks = 0; ks < 2; ++ks) {
          v2u a = __builtin_amdgcn_permlane32_swap(pw1[ks * 4 + 0], pw1[ks * 4 + 2], false, false);
          v2u c = __builtin_amdgcn_permlane32_swap(pw1[ks * 4 + 1], pw1[ks * 4 + 3], false, false);
          v4u fw; fw.x = a.x; fw.y = c.x; fw.z = a.y; fw.w = c.y;
          v8s pb = __builtin_bit_cast(v8s, fw);
          v8s vf0 = *(const v8s*)&Vlds[cur][l31][((((ks + 2) << 1) | h32) << 3) ^ swz];
          O0 = __builtin_amdgcn_mfma_f32_32x32x16_bf16(vf0, pb, O0, 0, 0, 0);
          v8s vf1 = *(const v8s*)&Vlds[cur][32 + l31][((((ks + 2) << 1) | h32) << 3) ^ swz];
          O1 = __builtin_amdgcn_mfma_f32_32x32x16_bf16(vf1, pb, O1, 0, 0, 0);
        }
      }
      __builtin_amdgcn_s_setprio(0);
    }

    __builtin_amdgcn_sched_barrier(0);
    __builtin_amdgcn_s_barrier();  // buf[cur] reads done before stage(s+2)
    __builtin_amdgcn_sched_barrier(0);
  }

  // Epilogue: unnormalized partial write (native layout, coalesced in q)
  int p = bh * 64 + qt * 4 + wave;
  uint32* Op = Opart + ((size_t)(sp * NP_ + p)) * 1024;
#pragma unroll
  for (int w = 0; w < 8; ++w) {
    int dpair = 4 * (w >> 1) + (w & 1) + 2 * h32;
    Op[dpair * 32 + l31] = pk_bf16(O0[2 * w], O0[2 * w + 1]);
    Op[(16 + dpair) * 32 + l31] = pk_bf16(O1[2 * w], O1[2 * w + 1]);
  }
  if (h32 == 0) Lsum[(size_t)(sp * NP_ + p) * 32 + l31] = L;

  // Folded residual pass-through: out[0:B*S*D] = residual
  {
    constexpr int F4 = (SPLITS == 2) ? 4 : 8;
    const float4* rs_ = (const float4*)residual;
    float4* rd_ = (float4*)res_out;
    size_t base = (size_t)bid * (256 * F4) + tid;
#pragma unroll
    for (int j = 0; j < F4; ++j) rd_[base + j * 256] = rs_[base + j * 256];
  }
}

// ---------------- merge partials -> z (bf16) ----------------
template <int SPLITS>
__global__ __launch_bounds__(128) void merge_kernel(
    const uint32* __restrict__ Opart, const float* __restrict__ Lsum,
    short* __restrict__ z) {
  int p = blockIdx.x;
  int tid = threadIdx.x;
  int qq = tid & 31, g = tid >> 5;

  float Lt = Lsum[(size_t)p * 32 + qq];
  if constexpr (SPLITS == 2) Lt += Lsum[((size_t)NP_ + p) * 32 + qq];
  float f = 1.f / Lt;

  __shared__ uint32 T[32][33];
#pragma unroll
  for (int j = 0; j < 8; ++j) {
    int dp = g * 8 + j;
    uint32 u0 = Opart[(size_t)p * 1024 + dp * 32 + qq];
    float lo = __uint_as_float(u0 << 16);
    float hi = __uint_as_float(u0 & 0xFFFF0000u);
    if constexpr (SPLITS == 2) {
      uint32 u1 = Opart[((size_t)NP_ + p) * 1024 + dp * 32 + qq];
      lo += __uint_as_float(u1 << 16);
      hi += __uint_as_float(u1 & 0xFFFF0000u);
    }
    T[qq][dp] = pk_bf16(lo * f, hi * f);
  }
  __syncthreads();
  int q2 = tid >> 2, c = (tid & 3) * 8;
  int srow = (p & 63) * 32 + q2;
  int b = p >> 10, h = (p >> 6) & 15;
  uint32* zp = (uint32*)z + ((size_t)(b * S_ + srow)) * (D_ / 2) + h * 32 + c;
#pragma unroll
  for (int j = 0; j < 8; ++j) zp[j] = T[q2][c + j];
}

// ------------- projection GEMM 128x128 (R14-proven): out = z @ Wt^T + b -----
__global__ __launch_bounds__(256) void proj_kernel(
    const short* __restrict__ z, const short* __restrict__ wt,
    const float* __restrict__ bias, float* __restrict__ out) {
  int bid = blockIdx.x;
  int bm = bid & 31, bn = bid >> 5;
  int tid = threadIdx.x;
  int wave = tid >> 6, lane = tid & 63, lh = lane >> 4, ll = lane & 15;
  int wr = wave >> 1, wc = wave & 1;

  __shared__ short Al[2][128][64];
  __shared__ short Bl[2][128][64];

  const int r8 = lane >> 3;
  const int scol = ((lane & 7) ^ r8) << 3;

  v4f acc[4][4];
#pragma unroll
  for (int m = 0; m < 4; ++m)
#pragma unroll
    for (int n = 0; n < 4; ++n) acc[m][n] = (v4f){0.f, 0.f, 0.f, 0.f};

  auto stage = [&](int kb, int bbuf) {
#pragma unroll
    for (int i = 0; i < 4; ++i) {
      int c = wave * 4 + i;
      gll16(z + (size_t)(bm * 128 + c * 8 + r8) * D_ + kb + scol, &Al[bbuf][c * 8][0]);
    }
#pragma unroll
    for (int i = 0; i < 4; ++i) {
      int c = wave * 4 + i;
      gll16(wt + (size_t)(bn * 128 + c * 8 + r8) * D_ + kb + scol, &Bl[bbuf][c * 8][0]);
    }
  };

  stage(0, 0);
  __syncthreads();

  for (int kt = 0; kt < D_ / 64; ++kt) {
    int bbuf = kt & 1;
    if (kt + 1 < D_ / 64) stage((kt + 1) * 64, bbuf ^ 1);
    v8s af[4][2], bf[4][2];
#pragma unroll
    for (int m = 0; m < 4; ++m) {
      int row = wr * 64 + m * 16 + ll;
#pragma unroll
      for (int c = 0; c < 2; ++c)
        af[m][c] = *(const v8s*)&Al[bbuf][row][(((c << 2) | lh) ^ (ll & 7)) << 3];
    }
#pragma unroll
    for (int n = 0; n < 4; ++n) {
      int row = wc * 64 + n * 16 + ll;
#pragma unroll
      for (int c = 0; c < 2; ++c)
        bf[n][c] = *(const v8s*)&Bl[bbuf][row][(((c << 2) | lh) ^ (ll & 7)) << 3];
    }
#pragma unroll
    for (int m = 0; m < 4; ++m)
#pragma unroll
      for (int n = 0; n < 4; ++n)
#pragma unroll
        for (int c = 0; c < 2; ++c)
          acc[m][n] = __builtin_amdgcn_mfma_f32_16x16x32_bf16(af[m][c], bf[n][c], acc[m][n], 0, 0, 0);
    __syncthreads();
  }

#pragma unroll
  for (int m = 0; m < 4; ++m) {
    int gr = bm * 128 + wr * 64 + m * 16 + lh * 4;
#pragma unroll
    for (int n = 0; n < 4; ++n) {
      int gc = bn * 128 + wc * 64 + n * 16 + ll;
      float bo = bias[gc];
#pragma unroll
      for (int r = 0; r < 4; ++r)
        out[(size_t)(gr + r) * D_ + gc] = acc[m][n][r] + bo;
    }
  }
}

extern "C" void kernel_launch(void* const* d_in, const int* in_sizes, int n_in,
                              void* d_out, int out_size, void* d_ws, size_t ws_size,
                              hipStream_t stream) {
  const float* residual = (const float*)d_in[0];
  const float* q = (const float*)d_in[1];
  const float* k = (const float*)d_in[2];
  const float* v = (const float*)d_in[3];
  const float* W = (const float*)d_in[4];
  const float* bO = (const float*)d_in[5];
  float* out = (float*)d_out;

  const size_t half = (size_t)B_ * S_ * D_;
  char* ws = (char*)d_ws;
  short* kbf = (short*)ws;                      // 8.4 MB (reused as z by merge)
  short* vtb = kbf + half;                      // 8.4 MB
  short* wtb = vtb + half;                      // 2.1 MB
  char* pbase = (char*)(wtb + (size_t)D_ * D_);
  const size_t opart_b = (size_t)NP_ * 1024 * 4;  // per slot: 8.4 MB
  const size_t l_b = (size_t)NP_ * 32 * 4;        // per slot: 256 KB
  const size_t base_b = (size_t)pbase - (size_t)ws;
  short* z = kbf;  // kbf dead after attn; merge writes z there

  cvt_all_kernel<<<3328, 256, 0, stream>>>(k, kbf, v, vtb, W, wtb);

  if (ws_size >= base_b + 2 * (opart_b + l_b)) {
    uint32* Opart = (uint32*)pbase;
    float* Lsum = (float*)(pbase + 2 * opart_b);
    attn_kernel<2><<<1024, 256, 0, stream>>>(q, kbf, vtb, Opart, Lsum, residual, out);
    merge_kernel<2><<<NP_, 128, 0, stream>>>(Opart, Lsum, z);
  } else {
    uint32* Opart = (uint32*)pbase;
    float* Lsum = (float*)(pbase + opart_b);
    attn_kernel<1><<<512, 256, 0, stream>>>(q, kbf, vtb, Opart, Lsum, residual, out);
    merge_kernel<1><<<NP_, 128, 0, stream>>>(Opart, Lsum, z);
  }
  proj_kernel<<<256, 256, 0, stream>>>(z, wtb, bO, out + half);
}